// Round 5
// baseline (235.083 us; speedup 1.0000x reference)
//
#include <hip/hip_runtime.h>
#include <stdint.h>

#define B_DIM 8
#define N_DIM 2048
#define F_DIM 128
#define LN_EPS 1e-5f

typedef __attribute__((ext_vector_type(8))) short short8;
typedef __attribute__((ext_vector_type(4))) float floatx4;

// full RNE fp32 -> bf16
__device__ __forceinline__ ushort f2bf(float f) {
    union { float f; uint32_t u; } c;
    c.f = f;
    uint32_t u = c.u;
    return (ushort)((u + 0x7FFFu + ((u >> 16) & 1u)) >> 16);
}

// fast round-half-up pack of two fp32 -> packed bf16x2
__device__ __forceinline__ uint32_t pk2bf(float a, float b) {
    union { float f; uint32_t u; } x, y;
    x.f = a; y.f = b;
    return ((x.u + 0x8000u) >> 16) | ((y.u + 0x8000u) & 0xFFFF0000u);
}

__device__ __forceinline__ short8 pack8(float4 lo, float4 hi) {
    union { uint32_t u[4]; short8 s; } r;
    r.u[0] = pk2bf(lo.x, lo.y);
    r.u[1] = pk2bf(lo.z, lo.w);
    r.u[2] = pk2bf(hi.x, hi.y);
    r.u[3] = pk2bf(hi.z, hi.w);
    return r.s;
}

// ---------------------------------------------------------------------------
// Single kernel, ZERO workspace use (probe: do the two 512-MiB d_ws poison
// fills, 156 us/iter, leave the timed region?).
//
// H = A@X (bf16 MFMA), P = H@W^T + b, LN(128), ReLU.  BM=32, BN=128, BK=64.
// The X-transpose is folded in: each block stages its own X k-tile
// (fp32, L2/XCD-hot) into a chunk-XOR-swizzled LDS tile Xs[64][17*8] and
// reads B-fragments as 8x ds_read_u16 column gathers at MFMA time.
//   write:  Xs[m][ (c ^ (m>>3))*8 + e ]   (c = f>>3)  -> 2-way banks (free)
//   gather: row = ks*32+q*8+r, chunk = (n>>3) ^ (ks*4+q) -> conflict-free
// A-path / As swizzle / MFMA / epilogue: verbatim from passing v2/v3.
// Double-buffered, 1 raw s_barrier + lgkmcnt(0) per K-tile; next-next tile
// global loads stay in flight across barriers (reg-set alternation).
// LDS 43 KB -> 3 blocks/CU.
// ---------------------------------------------------------------------------
__global__ __launch_bounds__(256, 3) void k_fused(const float* __restrict__ A,
                                                  const float* __restrict__ X,
                                                  const float* __restrict__ W,
                                                  const float* __restrict__ bias,
                                                  const float* __restrict__ gamma,
                                                  const float* __restrict__ beta,
                                                  float* __restrict__ out) {
    __shared__ __align__(16) char smem[43008];
    ushort* const As0 = (ushort*)smem;                 // 32x64 bf16 = 4 KB
    ushort* const As1 = (ushort*)(smem + 4096);
    ushort* const Xs0 = (ushort*)(smem + 8192);        // 64x136 bf16 = 17408 B
    ushort* const Xs1 = (ushort*)(smem + 25600);
    // epilogue aliases (valid after the post-K-loop __syncthreads):
    ushort* const Ht = (ushort*)smem;                  // 32*136 bf16 = 8704 B
    float (*const Pt)[132] = (float(*)[132])(smem + 9216);  // 32*132 f32

    const int t = threadIdx.x;
    const int lane = t & 63;
    const int w = t >> 6;            // wave 0..3
    const int q = lane >> 4;         // 0..3
    const int mr = lane & 15;        // 0..15

    const int bid = blockIdx.x;
    const int bb = bid & 7;          // batch -> XCD affinity (L2 keeps X slice)
    const int m0 = (bid >> 3) * 32;  // M-tile origin

    const float* Ab = A + ((size_t)bb * N_DIM + m0) * N_DIM;
    const float* Xb = X + (size_t)bb * N_DIM * F_DIM;

    // ---- A staging: row = t>>3 (32 rows), chunk c = t&7 (8 k's) ----
    const int ar = t >> 3;
    const int ac = t & 7;
    const float* a_src = Ab + (size_t)ar * N_DIM + ac * 8;
    const int a_off = ar * 64 + ((ac ^ (ar & 7)) * 8);

    // ---- X staging: pass p in {0,1}: m = 32p + (t>>3), f0 = (t&7)*16 ----
    const int xr = t >> 3;
    const int xc = (t & 7) * 16;
    const float* x_base0 = Xb + (size_t)xr * F_DIM + xc;
    const float* x_base1 = Xb + (size_t)(32 + xr) * F_DIM + xc;
    const int key0 = xr >> 3;        // m>>3 for p0 (0..3)
    const int key1 = 4 + (xr >> 3);  // m>>3 for p1 (4..7)
    const int xoff0 = xr * 136 + (((xc >> 3) ^ key0) * 8);
    const int xoff1 = xr * 136 + ((((xc >> 3) + 1) ^ key0) * 8);
    const int xoff2 = (32 + xr) * 136 + (((xc >> 3) ^ key1) * 8);
    const int xoff3 = (32 + xr) * 136 + ((((xc >> 3) + 1) ^ key1) * 8);

    floatx4 acc[2][2];
#pragma unroll
    for (int i = 0; i < 2; ++i)
#pragma unroll
        for (int j = 0; j < 2; ++j) acc[i][j] = (floatx4){0.f, 0.f, 0.f, 0.f};

    float4 X0a[4], X0b[4], A0v[2];   // register set 0 (even tiles)
    float4 X1a[4], X1b[4], A1v[2];   // register set 1 (odd tiles)

    auto issue = [&](int k0, float4* Xa, float4* Xc, float4* Av) {
        const float4* p0 = (const float4*)(x_base0 + (size_t)k0 * F_DIM);
        Xa[0] = p0[0]; Xa[1] = p0[1]; Xa[2] = p0[2]; Xa[3] = p0[3];
        const float4* p1 = (const float4*)(x_base1 + (size_t)k0 * F_DIM);
        Xc[0] = p1[0]; Xc[1] = p1[1]; Xc[2] = p1[2]; Xc[3] = p1[3];
        const float4* pa = (const float4*)(a_src + k0);
        Av[0] = pa[0]; Av[1] = pa[1];
    };
    auto packT = [&](const float4* Xa, const float4* Xc, const float4* Av,
                     ushort* Xs_, ushort* As_) {
        *(short8*)(Xs_ + xoff0) = pack8(Xa[0], Xa[1]);
        *(short8*)(Xs_ + xoff1) = pack8(Xa[2], Xa[3]);
        *(short8*)(Xs_ + xoff2) = pack8(Xc[0], Xc[1]);
        *(short8*)(Xs_ + xoff3) = pack8(Xc[2], Xc[3]);
        *(short8*)(As_ + a_off) = pack8(Av[0], Av[1]);
    };
    auto compute = [&](const ushort* Ac, const ushort* Xc) {
#pragma unroll
        for (int ks = 0; ks < 2; ++ks) {
            short8 af[2];
#pragma unroll
            for (int i = 0; i < 2; ++i) {
                int m = mr + i * 16;
                af[i] = *(const short8*)(Ac + m * 64 +
                                         (((ks * 4 + q) ^ (m & 7)) * 8));
            }
#pragma unroll
            for (int j = 0; j < 2; ++j) {
                int n = w * 32 + j * 16 + mr;
                union { ushort s[8]; short8 v; } u;
#pragma unroll
                for (int r = 0; r < 8; ++r)
                    u.s[r] = Xc[(ks * 32 + q * 8 + r) * 136 +
                                (((n >> 3) ^ (ks * 4 + q)) * 8) + (n & 7)];
                acc[0][j] = __builtin_amdgcn_mfma_f32_16x16x32_bf16(
                    af[0], u.v, acc[0][j], 0, 0, 0);
                acc[1][j] = __builtin_amdgcn_mfma_f32_16x16x32_bf16(
                    af[1], u.v, acc[1][j], 0, 0, 0);
            }
        }
    };

    // ---- prologue: tile 0 staged to buf0; tile 1 loads left in flight ----
    issue(0, X0a, X0b, A0v);
    packT(X0a, X0b, A0v, Xs0, As0);
    issue(64, X1a, X1b, A1v);
    asm volatile("s_waitcnt lgkmcnt(0)" ::: "memory");
    __builtin_amdgcn_s_barrier();

    // ---- main loop: tiles 0..29 (15 iters x 2); issues reach tile 31 ----
#pragma unroll 1
    for (int tt = 0; tt < 30; tt += 2) {
        // even: compute tile tt (buf0); land tile tt+1; prefetch tt+2
        compute(As0, Xs0);
        packT(X1a, X1b, A1v, Xs1, As1);
        issue((tt + 2) * 64, X0a, X0b, A0v);
        asm volatile("s_waitcnt lgkmcnt(0)" ::: "memory");
        __builtin_amdgcn_s_barrier();

        // odd: compute tile tt+1 (buf1); land tile tt+2; prefetch tt+3
        compute(As1, Xs1);
        packT(X0a, X0b, A0v, Xs0, As0);
        issue((tt + 3) * 64, X1a, X1b, A1v);
        asm volatile("s_waitcnt lgkmcnt(0)" ::: "memory");
        __builtin_amdgcn_s_barrier();
    }

    // ---- tail: tile 30 (buf0), then tile 31 (buf1) ----
    compute(As0, Xs0);
    packT(X1a, X1b, A1v, Xs1, As1);
    asm volatile("s_waitcnt lgkmcnt(0)" ::: "memory");
    __builtin_amdgcn_s_barrier();
    compute(As1, Xs1);
    __syncthreads();  // full drain before epilogue aliases the stage buffers

    // ---- scatter H tile (bf16). D layout: col=lane&15, row=q*4+reg [m89]
#pragma unroll
    for (int j = 0; j < 2; ++j) {
        int col = w * 32 + j * 16 + mr;
#pragma unroll
        for (int r = 0; r < 4; ++r) {
            Ht[(q * 4 + r) * 136 + col] = f2bf(acc[0][j][r]);
            Ht[(16 + q * 4 + r) * 136 + col] = f2bf(acc[1][j][r]);
        }
    }
    __syncthreads();

    // ---- P[32x128] = Ht @ W^T  (W fp32 from global, L1/L2-hot)
    floatx4 p[2][2];
#pragma unroll
    for (int i = 0; i < 2; ++i)
#pragma unroll
        for (int j = 0; j < 2; ++j) p[i][j] = (floatx4){0.f, 0.f, 0.f, 0.f};

#pragma unroll
    for (int ks = 0; ks < 4; ++ks) {
        short8 ha0 = *(const short8*)(Ht + mr * 136 + ks * 32 + q * 8);
        short8 ha1 = *(const short8*)(Ht + (mr + 16) * 136 + ks * 32 + q * 8);
#pragma unroll
        for (int j = 0; j < 2; ++j) {
            const float* wp = W + (w * 32 + j * 16 + mr) * F_DIM + ks * 32 + q * 8;
            short8 wb = pack8(((const float4*)wp)[0], ((const float4*)wp)[1]);
            p[0][j] = __builtin_amdgcn_mfma_f32_16x16x32_bf16(ha0, wb, p[0][j], 0, 0, 0);
            p[1][j] = __builtin_amdgcn_mfma_f32_16x16x32_bf16(ha1, wb, p[1][j], 0, 0, 0);
        }
    }

    // ---- bias add, scatter P (fp32) for row-major LN
#pragma unroll
    for (int j = 0; j < 2; ++j) {
        int col = w * 32 + j * 16 + mr;
        float bcol = bias[col];
#pragma unroll
        for (int r = 0; r < 4; ++r) {
            Pt[q * 4 + r][col] = p[0][j][r] + bcol;
            Pt[16 + q * 4 + r][col] = p[1][j][r] + bcol;
        }
    }
    __syncthreads();

    // ---- LayerNorm + ReLU: 8 lanes per row, 16 values each
    const int row = t >> 3;
    const int seg = t & 7;
    float v[16];
    float s = 0.f, s2 = 0.f;
#pragma unroll
    for (int u = 0; u < 16; ++u) {
        v[u] = Pt[row][seg * 16 + u];
        s += v[u];
        s2 += v[u] * v[u];
    }
    s += __shfl_xor(s, 1);  s2 += __shfl_xor(s2, 1);
    s += __shfl_xor(s, 2);  s2 += __shfl_xor(s2, 2);
    s += __shfl_xor(s, 4);  s2 += __shfl_xor(s2, 4);
    float mu = s * (1.0f / 128.0f);
    float var = s2 * (1.0f / 128.0f) - mu * mu;
    float rs = rsqrtf(var + LN_EPS);

    float4 o[4];
    float* of = (float*)o;
#pragma unroll
    for (int u = 0; u < 16; ++u) {
        int d = seg * 16 + u;
        float y = (v[u] - mu) * rs * gamma[d] + beta[d];
        of[u] = fmaxf(y, 0.0f);
    }
    float4* dst = (float4*)(out + ((size_t)bb * N_DIM + m0 + row) * F_DIM + seg * 16);
    dst[0] = o[0]; dst[1] = o[1]; dst[2] = o[2]; dst[3] = o[3];
}

// ---------------------------------------------------------------------------
extern "C" void kernel_launch(void* const* d_in, const int* in_sizes, int n_in,
                              void* d_out, int out_size, void* d_ws, size_t ws_size,
                              hipStream_t stream) {
    const float* A     = (const float*)d_in[0];
    const float* X     = (const float*)d_in[1];
    const float* W     = (const float*)d_in[2];
    const float* bias  = (const float*)d_in[3];
    const float* gamma = (const float*)d_in[4];
    const float* beta  = (const float*)d_in[5];
    float* out = (float*)d_out;

    (void)d_ws; (void)ws_size;  // workspace intentionally unused

    k_fused<<<dim3(512), 256, 0, stream>>>(A, X, W, bias, gamma, beta, out);
}

// Round 6
// 214.409 us; speedup vs baseline: 1.0964x; 1.0964x over previous
//
#include <hip/hip_runtime.h>
#include <stdint.h>

#define B_DIM 8
#define N_DIM 2048
#define F_DIM 128
#define LN_EPS 1e-5f

typedef __attribute__((ext_vector_type(8))) short short8;
typedef __attribute__((ext_vector_type(4))) float floatx4;

// full RNE fp32 -> bf16
__device__ __forceinline__ ushort f2bf(float f) {
    union { float f; uint32_t u; } c;
    c.f = f;
    uint32_t u = c.u;
    return (ushort)((u + 0x7FFFu + ((u >> 16) & 1u)) >> 16);
}

// fast round-half-up pack of two fp32 -> packed bf16x2
__device__ __forceinline__ uint32_t pk2bf(float a, float b) {
    union { float f; uint32_t u; } x, y;
    x.f = a; y.f = b;
    return ((x.u + 0x8000u) >> 16) | ((y.u + 0x8000u) & 0xFFFF0000u);
}

__device__ __forceinline__ short8 pack8(float4 lo, float4 hi) {
    union { uint32_t u[4]; short8 s; } r;
    r.u[0] = pk2bf(lo.x, lo.y);
    r.u[1] = pk2bf(lo.z, lo.w);
    r.u[2] = pk2bf(hi.x, hi.y);
    r.u[3] = pk2bf(hi.z, hi.w);
    return r.s;
}

__device__ __forceinline__ void load_lds16(const ushort* g, ushort* l) {
    __builtin_amdgcn_global_load_lds(
        (const __attribute__((address_space(1))) void*)g,
        (__attribute__((address_space(3))) void*)l,
        16, 0, 0);
}

// ---------------------------------------------------------------------------
// Kernel 1 (prep): Yt[b,d,k] = (X[b] @ W^T)^T in bf16.
// Associativity: A@X@W^T = A@(X@W^T) -> fold the tiny F-GEMM (0.5 GFLOP)
// into the prep pass; the main kernel becomes a single GEMM + LN.
// Per block: 64 k-rows x 128 d.  X rows staged to swizzled LDS (bf16),
// W rows packed in regs (L1/L2-hot, all blocks read the same 64 KB).
// ---------------------------------------------------------------------------
__global__ __launch_bounds__(256) void k_prep(const float* __restrict__ X,
                                              const float* __restrict__ W,
                                              ushort* __restrict__ Yt) {
    __shared__ __align__(16) ushort Xs[64 * 128];  // 16 KB
    const int t = threadIdx.x;
    const int lane = t & 63;
    const int w = t >> 6;
    const int q = lane >> 4;
    const int mr = lane & 15;

    const int b = blockIdx.x >> 5;         // 0..7
    const int k0 = (blockIdx.x & 31) * 64; // 0..1984

    // ---- stage X[k0..k0+64][0..128] -> Xs (chunk-XOR swizzle, as v2 As) ----
    const int r = t >> 2;            // 0..63
    const int f0 = (t & 3) * 32;     // 0,32,64,96
    const float* src = X + (((size_t)b * N_DIM) + k0 + r) * F_DIM + f0;
    float4 v[8];
#pragma unroll
    for (int p = 0; p < 8; ++p) v[p] = ((const float4*)src)[p];
#pragma unroll
    for (int c2 = 0; c2 < 4; ++c2) {
        int chunk = (f0 >> 3) + c2;
        *(short8*)(Xs + r * 128 + ((chunk ^ (r & 7)) * 8)) =
            pack8(v[2 * c2], v[2 * c2 + 1]);
    }
    __syncthreads();

    // ---- GEMM: acc[i][j], i over 64 k-rows (4x16), j over d (w*32+j*16) ----
    floatx4 acc[4][2];
#pragma unroll
    for (int i = 0; i < 4; ++i)
#pragma unroll
        for (int j = 0; j < 2; ++j) acc[i][j] = (floatx4){0.f, 0.f, 0.f, 0.f};

#pragma unroll
    for (int ks = 0; ks < 4; ++ks) {
        short8 af[4];
#pragma unroll
        for (int i = 0; i < 4; ++i) {
            int m = i * 16 + mr;
            af[i] = *(const short8*)(Xs + m * 128 + (((ks * 4 + q) ^ (m & 7)) * 8));
        }
#pragma unroll
        for (int j = 0; j < 2; ++j) {
            const float* wp = W + (w * 32 + j * 16 + mr) * F_DIM + ks * 32 + q * 8;
            short8 wb = pack8(((const float4*)wp)[0], ((const float4*)wp)[1]);
#pragma unroll
            for (int i = 0; i < 4; ++i)
                acc[i][j] = __builtin_amdgcn_mfma_f32_16x16x32_bf16(af[i], wb,
                                                                    acc[i][j], 0, 0, 0);
        }
    }

    // ---- write Yt (b, d, k) bf16; D layout: col(d)=mr-based, row(k)=q*4+r2 ----
#pragma unroll
    for (int i = 0; i < 4; ++i)
#pragma unroll
        for (int j = 0; j < 2; ++j) {
            int d = w * 32 + j * 16 + mr;
            union { ushort s[4]; uint2 u; } o;
#pragma unroll
            for (int r2 = 0; r2 < 4; ++r2) o.s[r2] = f2bf(acc[i][j][r2]);
            *(uint2*)(Yt + (((size_t)b * F_DIM) + d) * N_DIM + k0 + i * 16 + q * 4) =
                o.u;
        }
}

// ---------------------------------------------------------------------------
// Kernel 2 (fused): P = A@Y (bf16 MFMA, single GEMM), + bias, LN(128), ReLU.
// Main loop is byte-for-byte the proven v2 structure (Yt has Xt's layout):
// BM=32, BN=128(d), BK=128; counted-vmcnt double-buffer pipeline; XOR
// swizzles on As/Bs; glds 16B B staging.  Epilogue: the H/W-GEMM phases are
// GONE (associativity) -> bias scatter + LN + ReLU only.
// LDS 80 KB -> 2 blocks/CU.
// ---------------------------------------------------------------------------
__global__ __launch_bounds__(256, 2) void k_fused(const float* __restrict__ A,
                                                  const ushort* __restrict__ Yt,
                                                  const float* __restrict__ bias,
                                                  const float* __restrict__ gamma,
                                                  const float* __restrict__ beta,
                                                  float* __restrict__ out) {
    __shared__ __align__(16) char smem[81920];
    ushort* const As0 = (ushort*)smem;                    // 32x128 bf16, buf0
    ushort* const As1 = (ushort*)(smem + 8192);           // buf1
    ushort* const Bs0 = (ushort*)(smem + 16384);          // 128x128 bf16, buf0
    ushort* const Bs1 = (ushort*)(smem + 16384 + 32768);  // buf1
    float (*const Pt)[132] = (float(*)[132])smem;         // epilogue alias

    const int t = threadIdx.x;
    const int lane = t & 63;
    const int w = t >> 6;            // wave 0..3
    const int q = lane >> 4;         // 0..3
    const int mr = lane & 15;        // 0..15

    const int bid = blockIdx.x;
    const int bb = bid & 7;          // batch -> XCD affinity (L2 keeps Yt slice)
    const int m0 = (bid >> 3) * 32;  // M-tile origin

    const float* Ab = A + ((size_t)bb * N_DIM + m0) * N_DIM;
    const ushort* Yb = Yt + (size_t)bb * F_DIM * N_DIM;

    const int arow = t >> 3;
    const int asw_ = arow & 7;
    const float* a_src = Ab + (size_t)arow * N_DIM + (t & 7) * 16;
    const int a_off0 = arow * 128 + ((((t & 7) * 2) ^ asw_) * 8);
    const int a_off1 = arow * 128 + ((((t & 7) * 2 + 1) ^ asw_) * 8);

    const ushort* b_src[8];
    int b_off[8];
#pragma unroll
    for (int p = 0; p < 8; ++p) {
        int c = p * 256 + t;
        int n = c >> 4;
        int kc = (c & 15) ^ (n & 7);
        b_src[p] = Yb + (size_t)n * N_DIM + kc * 8;
        b_off[p] = c * 8;
    }

    floatx4 acc[2][2];
#pragma unroll
    for (int i = 0; i < 2; ++i)
#pragma unroll
        for (int j = 0; j < 2; ++j) acc[i][j] = (floatx4){0.f, 0.f, 0.f, 0.f};

    auto stageB = [&](int k0, ushort* Bn) {
#pragma unroll
        for (int p = 0; p < 8; ++p) load_lds16(b_src[p] + k0, Bn + b_off[p]);
    };
    auto packA = [&](float4 v0, float4 v1, float4 v2, float4 v3, ushort* An) {
        *(short8*)(An + a_off0) = pack8(v0, v1);
        *(short8*)(An + a_off1) = pack8(v2, v3);
    };
    auto compute = [&](const ushort* Ac, const ushort* Bc) {
#pragma unroll
        for (int ks = 0; ks < 4; ++ks) {
            short8 af[2], bfr[2];
#pragma unroll
            for (int i = 0; i < 2; ++i) {
                int m = mr + i * 16;
                af[i] = *(const short8*)(Ac + m * 128 + (((ks * 4 + q) ^ (m & 7)) * 8));
            }
#pragma unroll
            for (int j = 0; j < 2; ++j) {
                int n = w * 32 + j * 16 + mr;
                bfr[j] = *(const short8*)(Bc + n * 128 + (((ks * 4 + q) ^ (n & 7)) * 8));
            }
#pragma unroll
            for (int i = 0; i < 2; ++i)
#pragma unroll
                for (int j = 0; j < 2; ++j)
                    acc[i][j] = __builtin_amdgcn_mfma_f32_16x16x32_bf16(
                        af[i], bfr[j], acc[i][j], 0, 0, 0);
        }
    };

    float4 r0a, r0b, r0c, r0d, r1a, r1b, r1c, r1d;

    // ---- prologue: tile 0 -> buf0; A(1) loads left in flight
    {
        const float4* ap = (const float4*)(a_src);
        r0a = ap[0]; r0b = ap[1]; r0c = ap[2]; r0d = ap[3];
        stageB(0, Bs0);
        packA(r0a, r0b, r0c, r0d, As0);
        __builtin_amdgcn_sched_barrier(0);
        const float4* ap1 = (const float4*)(a_src + 128);
        r1a = ap1[0]; r1b = ap1[1]; r1c = ap1[2]; r1d = ap1[3];
    }
    asm volatile("s_waitcnt vmcnt(4) lgkmcnt(0)" ::: "memory");
    __builtin_amdgcn_s_barrier();

    // ---- main loop: tiles 0..13 (unroll x2)
#pragma unroll 1
    for (int tt = 0; tt < 14; tt += 2) {
        const int k0 = tt * 128;
        stageB(k0 + 128, Bs1);
        __builtin_amdgcn_sched_barrier(0);
        {
            const float4* ap = (const float4*)(a_src + k0 + 256);
            r0a = ap[0]; r0b = ap[1]; r0c = ap[2]; r0d = ap[3];
        }
        compute(As0, Bs0);
        packA(r1a, r1b, r1c, r1d, As1);
        asm volatile("s_waitcnt vmcnt(4) lgkmcnt(0)" ::: "memory");
        __builtin_amdgcn_s_barrier();

        stageB(k0 + 256, Bs0);
        __builtin_amdgcn_sched_barrier(0);
        {
            const float4* ap = (const float4*)(a_src + k0 + 384);
            r1a = ap[0]; r1b = ap[1]; r1c = ap[2]; r1d = ap[3];
        }
        compute(As1, Bs1);
        packA(r0a, r0b, r0c, r0d, As0);
        asm volatile("s_waitcnt vmcnt(4) lgkmcnt(0)" ::: "memory");
        __builtin_amdgcn_s_barrier();
    }

    // ---- tail: tile 14 (buf0) with last stage, then tile 15 (buf1)
    stageB(15 * 128, Bs1);
    compute(As0, Bs0);
    packA(r1a, r1b, r1c, r1d, As1);
    asm volatile("s_waitcnt vmcnt(0) lgkmcnt(0)" ::: "memory");
    __builtin_amdgcn_s_barrier();

    compute(As1, Bs1);
    __syncthreads();  // drain before Pt aliases the stage buffers

    // ---- bias add, scatter P (fp32) for row-major LN
    // D layout: col(d)=lane&15-based, row=q*4+reg [m89]
#pragma unroll
    for (int j = 0; j < 2; ++j) {
        int col = w * 32 + j * 16 + mr;
        float bcol = bias[col];
#pragma unroll
        for (int r = 0; r < 4; ++r) {
            Pt[q * 4 + r][col] = acc[0][j][r] + bcol;
            Pt[16 + q * 4 + r][col] = acc[1][j][r] + bcol;
        }
    }
    __syncthreads();

    // ---- LayerNorm + ReLU: 8 lanes per row, 16 values each
    const int row = t >> 3;
    const int seg = t & 7;
    float v[16];
    float s = 0.f, s2 = 0.f;
#pragma unroll
    for (int u = 0; u < 16; ++u) {
        v[u] = Pt[row][seg * 16 + u];
        s += v[u];
        s2 += v[u] * v[u];
    }
    s += __shfl_xor(s, 1);  s2 += __shfl_xor(s2, 1);
    s += __shfl_xor(s, 2);  s2 += __shfl_xor(s2, 2);
    s += __shfl_xor(s, 4);  s2 += __shfl_xor(s2, 4);
    float mu = s * (1.0f / 128.0f);
    float var = s2 * (1.0f / 128.0f) - mu * mu;
    float rs = rsqrtf(var + LN_EPS);

    float4 o[4];
    float* of = (float*)o;
#pragma unroll
    for (int u = 0; u < 16; ++u) {
        int d = seg * 16 + u;
        float y = (v[u] - mu) * rs * gamma[d] + beta[d];
        of[u] = fmaxf(y, 0.0f);
    }
    float4* dst = (float4*)(out + ((size_t)bb * N_DIM + m0 + row) * F_DIM + seg * 16);
    dst[0] = o[0]; dst[1] = o[1]; dst[2] = o[2]; dst[3] = o[3];
}

// ---------------------------------------------------------------------------
extern "C" void kernel_launch(void* const* d_in, const int* in_sizes, int n_in,
                              void* d_out, int out_size, void* d_ws, size_t ws_size,
                              hipStream_t stream) {
    const float* A     = (const float*)d_in[0];
    const float* X     = (const float*)d_in[1];
    const float* W     = (const float*)d_in[2];
    const float* bias  = (const float*)d_in[3];
    const float* gamma = (const float*)d_in[4];
    const float* beta  = (const float*)d_in[5];
    float* out = (float*)d_out;

    ushort* Yt = (ushort*)d_ws;  // 4 MB bf16 (fills are unconditional; use ws)

    k_prep<<<dim3(256), 256, 0, stream>>>(X, W, Yt);
    k_fused<<<dim3(512), 256, 0, stream>>>(A, Yt, bias, gamma, beta, out);
}